// Round 1
// baseline (1784.796 us; speedup 1.0000x reference)
//
#include <hip/hip_runtime.h>
#include <math.h>

// Problem constants
#define BSZ 64
#define NPTS 512
#define DIM 256
#define MROWS 32768      // BSZ*NPTS
#define TOTROWS 65536
#define BIGF 1.0e9f

// ws layout (float offsets)
#define E_OFF     0ull          // 16777216 floats: embeddings [A rows 0..32767][B rows 32768..65535]
#define K_OFF     16777216ull   // 16777216 floats: hidden H, later reused as K matrices
#define NORM_OFF  33554432ull   // 65536
#define U_OFF     33619968ull   // 32768
#define V_OFF     33652736ull   // 32768
#define ARGA_OFF  33685504ull   // 32768 (int)
#define ARGB_OFF  33718272ull   // 32768 (int)
#define ACC_OFF   33751040ull   // 4: [0]=S_inout [1]=S_sup [2]=S_pa

__device__ __forceinline__ float block_reduce_256(float val) {
    __shared__ float sh[4];
    int lane = threadIdx.x & 63;
    int wv = threadIdx.x >> 6;
#pragma unroll
    for (int off = 32; off > 0; off >>= 1) val += __shfl_down(val, off, 64);
    if (lane == 0) sh[wv] = val;
    __syncthreads();
    float r = 0.f;
    if (wv == 0 && lane < 4) r = sh[lane];
    if (wv == 0) {
        r += __shfl_down(r, 2, 64);
        r += __shfl_down(r, 1, 64);
    }
    return r;  // valid in thread 0
}

__global__ void zero_acc_kernel(float* acc) {
    if (threadIdx.x < 4) acc[threadIdx.x] = 0.f;
}

// argmax of 4 logits for A and B + sum of padding_mask_a
__global__ __launch_bounds__(256) void argmax_pa_kernel(
    const float* __restrict__ la, const float* __restrict__ lb,
    const float* __restrict__ pa, int* __restrict__ argA, int* __restrict__ argB,
    float* __restrict__ acc) {
    int i = blockIdx.x * 256 + threadIdx.x;  // 0..32767
    float4 a = *(const float4*)&la[(size_t)i * 4];
    float av[4] = {a.x, a.y, a.z, a.w};
    int ba = 0; float bv = av[0];
#pragma unroll
    for (int c = 1; c < 4; ++c) if (av[c] > bv) { bv = av[c]; ba = c; }
    argA[i] = ba;
    float4 b = *(const float4*)&lb[(size_t)i * 4];
    float bw[4] = {b.x, b.y, b.z, b.w};
    int bbi = 0; float bm = bw[0];
#pragma unroll
    for (int c = 1; c < 4; ++c) if (bw[c] > bm) { bm = bw[c]; bbi = c; }
    argB[i] = bbi;
    float p = pa[i];
#pragma unroll
    for (int off = 32; off > 0; off >>= 1) p += __shfl_down(p, off, 64);
    if ((threadIdx.x & 63) == 0) atomicAdd(&acc[2], p);
}

// Y = X @ W  (raw, no bias). X: rows x 256, W: 256 x 256. 64x64 block tile, 4x4 micro.
__global__ __launch_bounds__(256) void gemm_kernel(
    const float* __restrict__ X, const float* __restrict__ W, float* __restrict__ Y) {
    __shared__ __align__(16) float As[16][68];
    __shared__ __align__(16) float Bsh[16][64];
    const int t = threadIdx.x;
    const int tx = t & 15, ty = t >> 4;
    const int row0 = blockIdx.y * 64, col0 = blockIdx.x * 64;
    float acc[4][4] = {};
    for (int k0 = 0; k0 < 256; k0 += 16) {
        {
            int r = t >> 2, q = t & 3;
            float4 xv = *(const float4*)&X[(size_t)(row0 + r) * 256 + k0 + q * 4];
            As[q * 4 + 0][r] = xv.x; As[q * 4 + 1][r] = xv.y;
            As[q * 4 + 2][r] = xv.z; As[q * 4 + 3][r] = xv.w;
            int k = t >> 4, cq = t & 15;
            float4 wv = *(const float4*)&W[(size_t)(k0 + k) * 256 + col0 + cq * 4];
            *(float4*)&Bsh[k][cq * 4] = wv;
        }
        __syncthreads();
#pragma unroll
        for (int k = 0; k < 16; ++k) {
            float4 a4 = *(const float4*)&As[k][ty * 4];
            float4 b4 = *(const float4*)&Bsh[k][tx * 4];
            float avv[4] = {a4.x, a4.y, a4.z, a4.w};
            float bvv[4] = {b4.x, b4.y, b4.z, b4.w};
#pragma unroll
            for (int i = 0; i < 4; ++i)
#pragma unroll
                for (int j = 0; j < 4; ++j)
                    acc[i][j] = fmaf(avv[i], bvv[j], acc[i][j]);
        }
        __syncthreads();
    }
#pragma unroll
    for (int i = 0; i < 4; ++i) {
        float4 o; o.x = acc[i][0]; o.y = acc[i][1]; o.z = acc[i][2]; o.w = acc[i][3];
        *(float4*)&Y[(size_t)(row0 + ty * 4 + i) * 256 + col0 + tx * 4] = o;
    }
}

// in-place: y = LN(leaky_relu(y + bias)) * g + be ; optional row sq-norm output
__global__ __launch_bounds__(256) void bias_act_ln_kernel(
    float* __restrict__ Y, const float* __restrict__ bias,
    const float* __restrict__ gam, const float* __restrict__ bet,
    float* __restrict__ norms) {
    int lane = threadIdx.x & 63;
    int wv = threadIdx.x >> 6;
    int row = blockIdx.x * 4 + wv;
    float* y = Y + (size_t)row * 256;
    float4 x4 = *(float4*)&y[lane * 4];
    float4 b4 = *(const float4*)&bias[lane * 4];
    float h[4] = {x4.x + b4.x, x4.y + b4.y, x4.z + b4.z, x4.w + b4.w};
#pragma unroll
    for (int e = 0; e < 4; ++e) h[e] = h[e] >= 0.f ? h[e] : 0.01f * h[e];
    float s = h[0] + h[1] + h[2] + h[3];
    float sq = h[0] * h[0] + h[1] * h[1] + h[2] * h[2] + h[3] * h[3];
#pragma unroll
    for (int off = 32; off > 0; off >>= 1) {
        s += __shfl_down(s, off, 64);
        sq += __shfl_down(sq, off, 64);
    }
    s = __shfl(s, 0, 64); sq = __shfl(sq, 0, 64);
    float mean = s * (1.f / 256.f);
    float var = fmaxf(sq * (1.f / 256.f) - mean * mean, 0.f);
    float inv = rsqrtf(var + 1e-5f);
    float4 g4 = *(const float4*)&gam[lane * 4];
    float4 e4 = *(const float4*)&bet[lane * 4];
    float gv[4] = {g4.x, g4.y, g4.z, g4.w};
    float ev[4] = {e4.x, e4.y, e4.z, e4.w};
    float o[4]; float nr = 0.f;
#pragma unroll
    for (int e = 0; e < 4; ++e) { o[e] = (h[e] - mean) * inv * gv[e] + ev[e]; nr += o[e] * o[e]; }
    float4 o4; o4.x = o[0]; o4.y = o[1]; o4.z = o[2]; o4.w = o[3];
    *(float4*)&y[lane * 4] = o4;
    if (norms) {
#pragma unroll
        for (int off = 32; off > 0; off >>= 1) nr += __shfl_down(nr, off, 64);
        if (lane == 0) norms[row] = nr;
    }
}

// cost tile: cdist + pmv; accumulates (2*mask-1)*cc*pm; writes K = exp(-2*cc)
__global__ __launch_bounds__(256) void cost_kernel(
    const float* __restrict__ E, const float* __restrict__ norms,
    const int* __restrict__ argA, const int* __restrict__ argB,
    const float* __restrict__ pa, const float* __restrict__ pb,
    float* __restrict__ Kmat, float* __restrict__ acc) {
    __shared__ __align__(16) float As[16][68];
    __shared__ __align__(16) float Bs[16][68];
    const int t = threadIdx.x;
    const int tx = t & 15, ty = t >> 4;
    const int b = blockIdx.z;
    const int i0 = blockIdx.y * 64, j0 = blockIdx.x * 64;
    const float* eA = E + (size_t)b * 512 * 256;
    const float* eB = E + (size_t)(32768 + b * 512) * 256;
    float dot[4][4] = {};
    for (int k0 = 0; k0 < 256; k0 += 16) {
        int r = t >> 2, q = t & 3;
        float4 av = *(const float4*)&eA[(size_t)(i0 + r) * 256 + k0 + q * 4];
        As[q * 4 + 0][r] = av.x; As[q * 4 + 1][r] = av.y;
        As[q * 4 + 2][r] = av.z; As[q * 4 + 3][r] = av.w;
        float4 bv = *(const float4*)&eB[(size_t)(j0 + r) * 256 + k0 + q * 4];
        Bs[q * 4 + 0][r] = bv.x; Bs[q * 4 + 1][r] = bv.y;
        Bs[q * 4 + 2][r] = bv.z; Bs[q * 4 + 3][r] = bv.w;
        __syncthreads();
#pragma unroll
        for (int k = 0; k < 16; ++k) {
            float4 a4 = *(const float4*)&As[k][ty * 4];
            float4 b4 = *(const float4*)&Bs[k][tx * 4];
            float avv[4] = {a4.x, a4.y, a4.z, a4.w};
            float bvv[4] = {b4.x, b4.y, b4.z, b4.w};
#pragma unroll
            for (int i = 0; i < 4; ++i)
#pragma unroll
                for (int j = 0; j < 4; ++j)
                    dot[i][j] = fmaf(avv[i], bvv[j], dot[i][j]);
        }
        __syncthreads();
    }
    float nA[4], pA[4]; int cA[4];
    float nB[4], pB[4]; int cB[4];
#pragma unroll
    for (int i = 0; i < 4; ++i) {
        int row = i0 + ty * 4 + i;
        nA[i] = norms[b * 512 + row];
        pA[i] = pa[b * 512 + row];
        cA[i] = argA[b * 512 + row];
    }
#pragma unroll
    for (int j = 0; j < 4; ++j) {
        int col = j0 + tx * 4 + j;
        nB[j] = norms[32768 + b * 512 + col];
        pB[j] = pb[b * 512 + col];
        cB[j] = argB[b * 512 + col];
    }
    float part = 0.f;
#pragma unroll
    for (int i = 0; i < 4; ++i) {
        int row = i0 + ty * 4 + i;
        float kv[4];
#pragma unroll
        for (int j = 0; j < 4; ++j) {
            float d2 = nA[i] + nB[j] - 2.f * dot[i][j];
            float c = sqrtf(fmaxf(d2, 0.f));
            float pm = pA[i] * pB[j];
            float cc = c + (BIGF - BIGF * pm);
            float sgn = (cA[i] == cB[j]) ? 1.f : -1.f;
            part += cc * sgn * pm;
            kv[j] = expf(-2.f * cc);   // exp(-cc/REG), REG=0.5
        }
        float4 k4; k4.x = kv[0]; k4.y = kv[1]; k4.z = kv[2]; k4.w = kv[3];
        *(float4*)&Kmat[((size_t)b * 512 + row) * 512 + j0 + tx * 4] = k4;
    }
    float tot = block_reduce_256(part);
    if (threadIdx.x == 0) atomicAdd(&acc[0], tot);
}

__global__ __launch_bounds__(256) void init_u_kernel(float* __restrict__ u) {
    u[blockIdx.x * 256 + threadIdx.x] = 1.f / 512.f;
}

// v_j = (1/512) / sum_i K[i][j] * u_i  (column sums; coalesced)
__global__ __launch_bounds__(64) void sink_v_kernel(
    const float* __restrict__ Kmat, const float* __restrict__ u, float* __restrict__ v) {
    __shared__ float us[512];
    int b = blockIdx.y;
#pragma unroll
    for (int t = 0; t < 8; ++t) us[threadIdx.x + t * 64] = u[b * 512 + threadIdx.x + t * 64];
    __syncthreads();
    int j = blockIdx.x * 64 + threadIdx.x;
    const float* Kb = Kmat + (size_t)b * 262144;
    float s = 0.f;
#pragma unroll 8
    for (int i = 0; i < 512; ++i) s = fmaf(Kb[(size_t)i * 512 + j], us[i], s);
    v[b * 512 + j] = (1.f / 512.f) / s;
}

// u_i = (1/512) / sum_j K[i][j] * v_j  (row sums; wave per row)
__global__ __launch_bounds__(256) void sink_u_kernel(
    const float* __restrict__ Kmat, const float* __restrict__ v, float* __restrict__ u) {
    __shared__ float vs[512];
    int b = blockIdx.y;
    vs[threadIdx.x] = v[b * 512 + threadIdx.x];
    vs[threadIdx.x + 256] = v[b * 512 + 256 + threadIdx.x];
    __syncthreads();
    int lane = threadIdx.x & 63, wv = threadIdx.x >> 6;
    int i = blockIdx.x * 4 + wv;
    const float* Kr = Kmat + (size_t)b * 262144 + (size_t)i * 512;
    float s = 0.f;
#pragma unroll
    for (int tt = 0; tt < 8; ++tt) s = fmaf(Kr[tt * 64 + lane], vs[tt * 64 + lane], s);
#pragma unroll
    for (int off = 32; off > 0; off >>= 1) s += __shfl_down(s, off, 64);
    if (lane == 0) u[b * 512 + i] = (1.f / 512.f) / s;
}

// sup loss: sum (u_i K_ij v_j * 512 - rel)^2 * pa_i
__global__ __launch_bounds__(256) void sup_kernel(
    const float* __restrict__ Kmat, const float* __restrict__ u, const float* __restrict__ v,
    const float* __restrict__ rel, const float* __restrict__ pa, float* __restrict__ acc) {
    int idx = blockIdx.x * 256 + threadIdx.x;   // < 16,777,216
    int b = idx >> 18;
    int r = idx & 262143;
    int i = r >> 9;
    int j = r & 511;
    float K = Kmat[idx];
    float p = u[b * 512 + i] * K * v[b * 512 + j] * 512.f;
    float d = p - rel[idx];
    float tval = d * d * pa[b * 512 + i];
    float tot = block_reduce_256(tval);
    if (threadIdx.x == 0) atomicAdd(&acc[1], tot);
}

__global__ void final_kernel(const float* __restrict__ acc, float* __restrict__ out) {
    if (threadIdx.x == 0)
        out[0] = acc[0] * (1.f / 16777216.f) + 10.f * acc[1] / acc[2];
}

extern "C" void kernel_launch(void* const* d_in, const int* in_sizes, int n_in,
                              void* d_out, int out_size, void* d_ws, size_t ws_size,
                              hipStream_t stream) {
    const float* la  = (const float*)d_in[0];
    const float* lb  = (const float*)d_in[1];
    const float* xA  = (const float*)d_in[2];
    const float* xB  = (const float*)d_in[3];
    const float* rel = (const float*)d_in[4];
    const float* pa  = (const float*)d_in[5];
    const float* pb  = (const float*)d_in[6];
    const float* W1  = (const float*)d_in[7];
    const float* b1  = (const float*)d_in[8];
    const float* g1  = (const float*)d_in[9];
    const float* be1 = (const float*)d_in[10];
    const float* W2  = (const float*)d_in[11];
    const float* b2  = (const float*)d_in[12];
    const float* g2  = (const float*)d_in[13];
    const float* be2 = (const float*)d_in[14];
    float* out = (float*)d_out;

    float* ws = (float*)d_ws;
    float* E     = ws + E_OFF;
    float* Kbuf  = ws + K_OFF;      // H, then K
    float* norms = ws + NORM_OFF;
    float* u     = ws + U_OFF;
    float* v     = ws + V_OFF;
    int* argA    = (int*)(ws + ARGA_OFF);
    int* argB    = (int*)(ws + ARGB_OFF);
    float* acc   = ws + ACC_OFF;

    zero_acc_kernel<<<1, 64, 0, stream>>>(acc);
    argmax_pa_kernel<<<128, 256, 0, stream>>>(la, lb, pa, argA, argB, acc);

    // layer 1: H_raw = [xA;xB] @ W1  -> Kbuf
    gemm_kernel<<<dim3(4, 512), 256, 0, stream>>>(xA, W1, Kbuf);
    gemm_kernel<<<dim3(4, 512), 256, 0, stream>>>(xB, W1, Kbuf + (size_t)MROWS * DIM);
    bias_act_ln_kernel<<<16384, 256, 0, stream>>>(Kbuf, b1, g1, be1, nullptr);
    // layer 2: E_raw = H @ W2 -> E
    gemm_kernel<<<dim3(4, 1024), 256, 0, stream>>>(Kbuf, W2, E);
    bias_act_ln_kernel<<<16384, 256, 0, stream>>>(E, b2, g2, be2, norms);

    // cost + K (overwrites Kbuf; H no longer needed)
    cost_kernel<<<dim3(8, 8, 64), 256, 0, stream>>>(E, norms, argA, argB, pa, pb, Kbuf, acc);

    // sinkhorn: u=1/512; 10x { v = b/(K^T u); u = a/(K v) }
    init_u_kernel<<<128, 256, 0, stream>>>(u);
    for (int it = 0; it < 10; ++it) {
        sink_v_kernel<<<dim3(8, 64), 64, 0, stream>>>(Kbuf, u, v);
        sink_u_kernel<<<dim3(128, 64), 256, 0, stream>>>(Kbuf, v, u);
    }

    sup_kernel<<<65536, 256, 0, stream>>>(Kbuf, u, v, rel, pa, acc);
    final_kernel<<<1, 64, 0, stream>>>(acc, out);
}

// Round 2
// 812.370 us; speedup vs baseline: 2.1970x; 2.1970x over previous
//
#include <hip/hip_runtime.h>
#include <math.h>

// Problem constants
#define BSZ 64
#define NPTS 512
#define DIM 256
#define MROWS 32768      // BSZ*NPTS
#define TOTROWS 65536
#define BIGF 1.0e9f

// ws layout (float offsets)
#define E_OFF     0ull          // 16777216 floats: embeddings [A rows 0..32767][B rows 32768..65535]
#define K_OFF     16777216ull   // 16777216 floats: hidden H, later reused as K matrices
#define NORM_OFF  33554432ull   // 65536
#define U_OFF     33619968ull   // 32768
#define V_OFF     33652736ull   // 32768
#define ARGA_OFF  33685504ull   // 32768 (int)
#define ARGB_OFF  33718272ull   // 32768 (int)
#define ACC_OFF   33751040ull   // 321 floats: [0]=S_pa [1..64]=S_inout per batch [65..320]=S_sup slots

#define ACC_PA   0
#define ACC_IN   1     // 64 slots
#define ACC_SUP  65    // 256 slots
#define ACC_CNT  321

// re-entrant: safe to call multiple times in one block
__device__ __forceinline__ float block_reduce_256(float val) {
    __shared__ float sh[4];
    int lane = threadIdx.x & 63;
    int wv = threadIdx.x >> 6;
    __syncthreads();
#pragma unroll
    for (int off = 32; off > 0; off >>= 1) val += __shfl_down(val, off, 64);
    if (lane == 0) sh[wv] = val;
    __syncthreads();
    float r = 0.f;
    if (wv == 0 && lane < 4) r = sh[lane];
    if (wv == 0) {
        r += __shfl_down(r, 2, 64);
        r += __shfl_down(r, 1, 64);
    }
    return r;  // valid in thread 0
}

__global__ void zero_acc_kernel(float* acc) {
    int t = blockIdx.x * 256 + threadIdx.x;
    if (t < ACC_CNT) acc[t] = 0.f;
}

// argmax of 4 logits for A and B + sum of padding_mask_a
__global__ __launch_bounds__(256) void argmax_pa_kernel(
    const float* __restrict__ la, const float* __restrict__ lb,
    const float* __restrict__ pa, int* __restrict__ argA, int* __restrict__ argB,
    float* __restrict__ acc) {
    int i = blockIdx.x * 256 + threadIdx.x;  // 0..32767
    float4 a = *(const float4*)&la[(size_t)i * 4];
    float av[4] = {a.x, a.y, a.z, a.w};
    int ba = 0; float bv = av[0];
#pragma unroll
    for (int c = 1; c < 4; ++c) if (av[c] > bv) { bv = av[c]; ba = c; }
    argA[i] = ba;
    float4 b = *(const float4*)&lb[(size_t)i * 4];
    float bw[4] = {b.x, b.y, b.z, b.w};
    int bbi = 0; float bm = bw[0];
#pragma unroll
    for (int c = 1; c < 4; ++c) if (bw[c] > bm) { bm = bw[c]; bbi = c; }
    argB[i] = bbi;
    float p = pa[i];
#pragma unroll
    for (int off = 32; off > 0; off >>= 1) p += __shfl_down(p, off, 64);
    if ((threadIdx.x & 63) == 0) atomicAdd(&acc[ACC_PA], p);
}

// Y = X @ W  (raw, no bias). X: rows x 256, W: 256 x 256. 64x64 block tile, 4x4 micro.
__global__ __launch_bounds__(256) void gemm_kernel(
    const float* __restrict__ X, const float* __restrict__ W, float* __restrict__ Y) {
    __shared__ __align__(16) float As[16][68];
    __shared__ __align__(16) float Bsh[16][64];
    const int t = threadIdx.x;
    const int tx = t & 15, ty = t >> 4;
    const int row0 = blockIdx.y * 64, col0 = blockIdx.x * 64;
    float acc[4][4] = {};
    for (int k0 = 0; k0 < 256; k0 += 16) {
        {
            int r = t >> 2, q = t & 3;
            float4 xv = *(const float4*)&X[(size_t)(row0 + r) * 256 + k0 + q * 4];
            As[q * 4 + 0][r] = xv.x; As[q * 4 + 1][r] = xv.y;
            As[q * 4 + 2][r] = xv.z; As[q * 4 + 3][r] = xv.w;
            int k = t >> 4, cq = t & 15;
            float4 wv = *(const float4*)&W[(size_t)(k0 + k) * 256 + col0 + cq * 4];
            *(float4*)&Bsh[k][cq * 4] = wv;
        }
        __syncthreads();
#pragma unroll
        for (int k = 0; k < 16; ++k) {
            float4 a4 = *(const float4*)&As[k][ty * 4];
            float4 b4 = *(const float4*)&Bsh[k][tx * 4];
            float avv[4] = {a4.x, a4.y, a4.z, a4.w};
            float bvv[4] = {b4.x, b4.y, b4.z, b4.w};
#pragma unroll
            for (int i = 0; i < 4; ++i)
#pragma unroll
                for (int j = 0; j < 4; ++j)
                    acc[i][j] = fmaf(avv[i], bvv[j], acc[i][j]);
        }
        __syncthreads();
    }
#pragma unroll
    for (int i = 0; i < 4; ++i) {
        float4 o; o.x = acc[i][0]; o.y = acc[i][1]; o.z = acc[i][2]; o.w = acc[i][3];
        *(float4*)&Y[(size_t)(row0 + ty * 4 + i) * 256 + col0 + tx * 4] = o;
    }
}

// in-place: y = LN(leaky_relu(y + bias)) * g + be ; optional row sq-norm output
__global__ __launch_bounds__(256) void bias_act_ln_kernel(
    float* __restrict__ Y, const float* __restrict__ bias,
    const float* __restrict__ gam, const float* __restrict__ bet,
    float* __restrict__ norms) {
    int lane = threadIdx.x & 63;
    int wv = threadIdx.x >> 6;
    int row = blockIdx.x * 4 + wv;
    float* y = Y + (size_t)row * 256;
    float4 x4 = *(float4*)&y[lane * 4];
    float4 b4 = *(const float4*)&bias[lane * 4];
    float h[4] = {x4.x + b4.x, x4.y + b4.y, x4.z + b4.z, x4.w + b4.w};
#pragma unroll
    for (int e = 0; e < 4; ++e) h[e] = h[e] >= 0.f ? h[e] : 0.01f * h[e];
    float s = h[0] + h[1] + h[2] + h[3];
    float sq = h[0] * h[0] + h[1] * h[1] + h[2] * h[2] + h[3] * h[3];
#pragma unroll
    for (int off = 32; off > 0; off >>= 1) {
        s += __shfl_down(s, off, 64);
        sq += __shfl_down(sq, off, 64);
    }
    s = __shfl(s, 0, 64); sq = __shfl(sq, 0, 64);
    float mean = s * (1.f / 256.f);
    float var = fmaxf(sq * (1.f / 256.f) - mean * mean, 0.f);
    float inv = rsqrtf(var + 1e-5f);
    float4 g4 = *(const float4*)&gam[lane * 4];
    float4 e4 = *(const float4*)&bet[lane * 4];
    float gv[4] = {g4.x, g4.y, g4.z, g4.w};
    float ev[4] = {e4.x, e4.y, e4.z, e4.w};
    float o[4]; float nr = 0.f;
#pragma unroll
    for (int e = 0; e < 4; ++e) { o[e] = (h[e] - mean) * inv * gv[e] + ev[e]; nr += o[e] * o[e]; }
    float4 o4; o4.x = o[0]; o4.y = o[1]; o4.z = o[2]; o4.w = o[3];
    *(float4*)&y[lane * 4] = o4;
    if (norms) {
#pragma unroll
        for (int off = 32; off > 0; off >>= 1) nr += __shfl_down(nr, off, 64);
        if (lane == 0) norms[row] = nr;
    }
}

// cost tile: cdist + pmv; accumulates (2*mask-1)*cc*pm; writes K = exp(-2*cc)
__global__ __launch_bounds__(256) void cost_kernel(
    const float* __restrict__ E, const float* __restrict__ norms,
    const int* __restrict__ argA, const int* __restrict__ argB,
    const float* __restrict__ pa, const float* __restrict__ pb,
    float* __restrict__ Kmat, float* __restrict__ acc) {
    __shared__ __align__(16) float As[16][68];
    __shared__ __align__(16) float Bs[16][68];
    const int t = threadIdx.x;
    const int tx = t & 15, ty = t >> 4;
    const int b = blockIdx.z;
    const int i0 = blockIdx.y * 64, j0 = blockIdx.x * 64;
    const float* eA = E + (size_t)b * 512 * 256;
    const float* eB = E + (size_t)(32768 + b * 512) * 256;
    float dot[4][4] = {};
    for (int k0 = 0; k0 < 256; k0 += 16) {
        int r = t >> 2, q = t & 3;
        float4 av = *(const float4*)&eA[(size_t)(i0 + r) * 256 + k0 + q * 4];
        As[q * 4 + 0][r] = av.x; As[q * 4 + 1][r] = av.y;
        As[q * 4 + 2][r] = av.z; As[q * 4 + 3][r] = av.w;
        float4 bv = *(const float4*)&eB[(size_t)(j0 + r) * 256 + k0 + q * 4];
        Bs[q * 4 + 0][r] = bv.x; Bs[q * 4 + 1][r] = bv.y;
        Bs[q * 4 + 2][r] = bv.z; Bs[q * 4 + 3][r] = bv.w;
        __syncthreads();
#pragma unroll
        for (int k = 0; k < 16; ++k) {
            float4 a4 = *(const float4*)&As[k][ty * 4];
            float4 b4 = *(const float4*)&Bs[k][tx * 4];
            float avv[4] = {a4.x, a4.y, a4.z, a4.w};
            float bvv[4] = {b4.x, b4.y, b4.z, b4.w};
#pragma unroll
            for (int i = 0; i < 4; ++i)
#pragma unroll
                for (int j = 0; j < 4; ++j)
                    dot[i][j] = fmaf(avv[i], bvv[j], dot[i][j]);
        }
        __syncthreads();
    }
    float nA[4], pA[4]; int cA[4];
    float nB[4], pB[4]; int cB[4];
#pragma unroll
    for (int i = 0; i < 4; ++i) {
        int row = i0 + ty * 4 + i;
        nA[i] = norms[b * 512 + row];
        pA[i] = pa[b * 512 + row];
        cA[i] = argA[b * 512 + row];
    }
#pragma unroll
    for (int j = 0; j < 4; ++j) {
        int col = j0 + tx * 4 + j;
        nB[j] = norms[32768 + b * 512 + col];
        pB[j] = pb[b * 512 + col];
        cB[j] = argB[b * 512 + col];
    }
    float part = 0.f;
#pragma unroll
    for (int i = 0; i < 4; ++i) {
        int row = i0 + ty * 4 + i;
        float kv[4];
#pragma unroll
        for (int j = 0; j < 4; ++j) {
            float d2 = nA[i] + nB[j] - 2.f * dot[i][j];
            float c = sqrtf(fmaxf(d2, 0.f));
            float pm = pA[i] * pB[j];
            float cc = c + (BIGF - BIGF * pm);
            float sgn = (cA[i] == cB[j]) ? 1.f : -1.f;
            part += cc * sgn * pm;
            kv[j] = expf(-2.f * cc);   // exp(-cc/REG), REG=0.5
        }
        float4 k4; k4.x = kv[0]; k4.y = kv[1]; k4.z = kv[2]; k4.w = kv[3];
        *(float4*)&Kmat[((size_t)b * 512 + row) * 512 + j0 + tx * 4] = k4;
    }
    float tot = block_reduce_256(part);
    if (threadIdx.x == 0) atomicAdd(&acc[ACC_IN + b], tot);   // 64 blocks per slot
}

__global__ __launch_bounds__(256) void init_u_kernel(float* __restrict__ u) {
    u[blockIdx.x * 256 + threadIdx.x] = 1.f / 512.f;
}

// v_j = (1/512) / sum_i K[i][j] * u_i  (column sums; 4 row-chunk waves per 64 cols)
__global__ __launch_bounds__(256) void sink_v_kernel(
    const float* __restrict__ Kmat, const float* __restrict__ u, float* __restrict__ v) {
    __shared__ float us[512];
    __shared__ float part[4][64];
    int t = threadIdx.x;
    int b = blockIdx.y;
    us[t] = u[b * 512 + t];
    us[t + 256] = u[b * 512 + 256 + t];
    __syncthreads();
    int lane = t & 63, wv = t >> 6;
    int j = blockIdx.x * 64 + lane;
    const float* Kb = Kmat + (size_t)b * 262144;
    float s = 0.f;
    int i0 = wv * 128;
#pragma unroll 8
    for (int i = i0; i < i0 + 128; ++i) s = fmaf(Kb[(size_t)i * 512 + j], us[i], s);
    part[wv][lane] = s;
    __syncthreads();
    if (wv == 0) {
        float tot = part[0][lane] + part[1][lane] + part[2][lane] + part[3][lane];
        v[b * 512 + j] = (1.f / 512.f) / tot;
    }
}

// u_i = (1/512) / sum_j K[i][j] * v_j  (row sums; wave per row)
__global__ __launch_bounds__(256) void sink_u_kernel(
    const float* __restrict__ Kmat, const float* __restrict__ v, float* __restrict__ u) {
    __shared__ float vs[512];
    int b = blockIdx.y;
    vs[threadIdx.x] = v[b * 512 + threadIdx.x];
    vs[threadIdx.x + 256] = v[b * 512 + 256 + threadIdx.x];
    __syncthreads();
    int lane = threadIdx.x & 63, wv = threadIdx.x >> 6;
    int i = blockIdx.x * 4 + wv;
    const float* Kr = Kmat + (size_t)b * 262144 + (size_t)i * 512;
    float s = 0.f;
#pragma unroll
    for (int tt = 0; tt < 8; ++tt) s = fmaf(Kr[tt * 64 + lane], vs[tt * 64 + lane], s);
#pragma unroll
    for (int off = 32; off > 0; off >>= 1) s += __shfl_down(s, off, 64);
    if (lane == 0) u[b * 512 + i] = (1.f / 512.f) / s;
}

// sup loss: sum (u_i K_ij v_j * 512 - rel)^2 * pa_i ; grid-stride float4,
// one spread-slot atomic per block (fix: was 65536 same-address atomics = 800us)
__global__ __launch_bounds__(256) void sup_kernel(
    const float* __restrict__ Kmat, const float* __restrict__ u, const float* __restrict__ v,
    const float* __restrict__ rel, const float* __restrict__ pa, float* __restrict__ acc) {
    const int nthreads = 4096 * 256;           // 1,048,576
    int tid = blockIdx.x * 256 + threadIdx.x;
    float part = 0.f;
#pragma unroll
    for (int k = 0; k < 4; ++k) {
        int i4 = tid + k * nthreads;           // float4 index < 4,194,304
        int e = i4 * 4;                        // element index
        int b = e >> 18;
        int i = (e >> 9) & 511;
        int j0 = e & 511;
        float4 K4 = *(const float4*)&Kmat[(size_t)i4 * 4];
        float4 r4 = *(const float4*)&rel[(size_t)i4 * 4];
        float4 v4 = *(const float4*)&v[b * 512 + j0];
        float ui = u[b * 512 + i] * 512.f;
        float pai = pa[b * 512 + i];
        float d0 = ui * K4.x * v4.x - r4.x;
        float d1 = ui * K4.y * v4.y - r4.y;
        float d2 = ui * K4.z * v4.z - r4.z;
        float d3 = ui * K4.w * v4.w - r4.w;
        part += (d0 * d0 + d1 * d1 + d2 * d2 + d3 * d3) * pai;
    }
    float tot = block_reduce_256(part);
    if (threadIdx.x == 0) atomicAdd(&acc[ACC_SUP + (blockIdx.x & 255)], tot);
}

__global__ __launch_bounds__(256) void final_kernel(const float* __restrict__ acc,
                                                    float* __restrict__ out) {
    int t = threadIdx.x;
    float vin = (t < 64) ? acc[ACC_IN + t] : 0.f;
    float sIn = block_reduce_256(vin);          // valid thread 0
    float vsup = acc[ACC_SUP + t];
    float sSup = block_reduce_256(vsup);        // valid thread 0
    if (t == 0)
        out[0] = sIn * (1.f / 16777216.f) + 10.f * sSup / acc[ACC_PA];
}

extern "C" void kernel_launch(void* const* d_in, const int* in_sizes, int n_in,
                              void* d_out, int out_size, void* d_ws, size_t ws_size,
                              hipStream_t stream) {
    const float* la  = (const float*)d_in[0];
    const float* lb  = (const float*)d_in[1];
    const float* xA  = (const float*)d_in[2];
    const float* xB  = (const float*)d_in[3];
    const float* rel = (const float*)d_in[4];
    const float* pa  = (const float*)d_in[5];
    const float* pb  = (const float*)d_in[6];
    const float* W1  = (const float*)d_in[7];
    const float* b1  = (const float*)d_in[8];
    const float* g1  = (const float*)d_in[9];
    const float* be1 = (const float*)d_in[10];
    const float* W2  = (const float*)d_in[11];
    const float* b2  = (const float*)d_in[12];
    const float* g2  = (const float*)d_in[13];
    const float* be2 = (const float*)d_in[14];
    float* out = (float*)d_out;

    float* ws = (float*)d_ws;
    float* E     = ws + E_OFF;
    float* Kbuf  = ws + K_OFF;      // H, then K
    float* norms = ws + NORM_OFF;
    float* u     = ws + U_OFF;
    float* v     = ws + V_OFF;
    int* argA    = (int*)(ws + ARGA_OFF);
    int* argB    = (int*)(ws + ARGB_OFF);
    float* acc   = ws + ACC_OFF;

    zero_acc_kernel<<<2, 256, 0, stream>>>(acc);
    argmax_pa_kernel<<<128, 256, 0, stream>>>(la, lb, pa, argA, argB, acc);

    // layer 1: H_raw = [xA;xB] @ W1  -> Kbuf
    gemm_kernel<<<dim3(4, 512), 256, 0, stream>>>(xA, W1, Kbuf);
    gemm_kernel<<<dim3(4, 512), 256, 0, stream>>>(xB, W1, Kbuf + (size_t)MROWS * DIM);
    bias_act_ln_kernel<<<16384, 256, 0, stream>>>(Kbuf, b1, g1, be1, nullptr);
    // layer 2: E_raw = H @ W2 -> E
    gemm_kernel<<<dim3(4, 1024), 256, 0, stream>>>(Kbuf, W2, E);
    bias_act_ln_kernel<<<16384, 256, 0, stream>>>(E, b2, g2, be2, norms);

    // cost + K (overwrites Kbuf; H no longer needed)
    cost_kernel<<<dim3(8, 8, 64), 256, 0, stream>>>(E, norms, argA, argB, pa, pb, Kbuf, acc);

    // sinkhorn: u=1/512; 10x { v = b/(K^T u); u = a/(K v) }
    init_u_kernel<<<128, 256, 0, stream>>>(u);
    for (int it = 0; it < 10; ++it) {
        sink_v_kernel<<<dim3(8, 64), 256, 0, stream>>>(Kbuf, u, v);
        sink_u_kernel<<<dim3(128, 64), 256, 0, stream>>>(Kbuf, v, u);
    }

    sup_kernel<<<4096, 256, 0, stream>>>(Kbuf, u, v, rel, pa, acc);
    final_kernel<<<1, 256, 0, stream>>>(acc, out);
}

// Round 3
// 513.123 us; speedup vs baseline: 3.4783x; 1.5832x over previous
//
#include <hip/hip_runtime.h>
#include <math.h>

// Problem constants
#define BSZ 64
#define NPTS 512
#define DIM 256
#define MROWS 32768      // BSZ*NPTS
#define TOTROWS 65536
#define BIGF 1.0e9f

typedef __bf16 bf16x8 __attribute__((ext_vector_type(8)));
typedef float  f32x4  __attribute__((ext_vector_type(4)));

// ws layout (float offsets)
#define KB_OFF    0ull          // 8388608 floats as ushort[16777216]: Ybf1 -> Ybf2 -> K(bf16)
#define X_OFF     8388608ull    // 8388608 floats as ushort[16777216]: Xbf -> Ebf
#define H_OFF     16777216ull   // 8388608 floats as ushort[16777216]: Hbf
#define NORM_OFF  25165824ull   // 65536 f32
#define U_OFF     25231360ull   // 32768 f32
#define V_OFF     25264128ull   // 32768 f32
#define ARGA_OFF  25296896ull   // 32768 int
#define ARGB_OFF  25329664ull   // 32768 int
#define ACC_OFF   25362432ull   // 321 f32
#define WT1_OFF   25362944ull   // 32768 floats as ushort[65536]
#define WT2_OFF   25395712ull   // 32768 floats as ushort[65536]

#define ACC_PA   0
#define ACC_IN   1     // 64 slots
#define ACC_SUP  65    // 256 slots
#define ACC_CNT  321

__device__ __forceinline__ float bf2f(unsigned short h) {
    return __uint_as_float(((unsigned int)h) << 16);
}
__device__ __forceinline__ unsigned short f2bf(float f) {
    unsigned int u = __float_as_uint(f);
    u = (u + 0x7FFFu + ((u >> 16) & 1u)) >> 16;
    return (unsigned short)u;
}

// re-entrant
__device__ __forceinline__ float block_reduce_256(float val) {
    __shared__ float sh[4];
    int lane = threadIdx.x & 63;
    int wv = threadIdx.x >> 6;
    __syncthreads();
#pragma unroll
    for (int off = 32; off > 0; off >>= 1) val += __shfl_down(val, off, 64);
    if (lane == 0) sh[wv] = val;
    __syncthreads();
    float r = 0.f;
    if (wv == 0 && lane < 4) r = sh[lane];
    if (wv == 0) {
        r += __shfl_down(r, 2, 64);
        r += __shfl_down(r, 1, 64);
    }
    return r;  // valid in thread 0
}

__global__ void zero_acc_kernel(float* acc) {
    int t = blockIdx.x * 256 + threadIdx.x;
    if (t < ACC_CNT) acc[t] = 0.f;
}

__global__ __launch_bounds__(256) void argmax_pa_kernel(
    const float* __restrict__ la, const float* __restrict__ lb,
    const float* __restrict__ pa, int* __restrict__ argA, int* __restrict__ argB,
    float* __restrict__ acc) {
    int i = blockIdx.x * 256 + threadIdx.x;
    float4 a = *(const float4*)&la[(size_t)i * 4];
    float av[4] = {a.x, a.y, a.z, a.w};
    int ba = 0; float bv = av[0];
#pragma unroll
    for (int c = 1; c < 4; ++c) if (av[c] > bv) { bv = av[c]; ba = c; }
    argA[i] = ba;
    float4 b = *(const float4*)&lb[(size_t)i * 4];
    float bw[4] = {b.x, b.y, b.z, b.w};
    int bbi = 0; float bm = bw[0];
#pragma unroll
    for (int c = 1; c < 4; ++c) if (bw[c] > bm) { bm = bw[c]; bbi = c; }
    argB[i] = bbi;
    float p = pa[i];
#pragma unroll
    for (int off = 32; off > 0; off >>= 1) p += __shfl_down(p, off, 64);
    if ((threadIdx.x & 63) == 0) atomicAdd(&acc[ACC_PA], p);
}

// f32 -> bf16 bulk cast; n4 = count of float4 groups, grid 2048x256, 4 groups/thread
__global__ __launch_bounds__(256) void cast_bf_kernel(
    const float* __restrict__ src, unsigned short* __restrict__ dst) {
    int tid = blockIdx.x * 256 + threadIdx.x;      // < 524288
#pragma unroll
    for (int k = 0; k < 4; ++k) {
        int i4 = tid + k * 524288;                 // < 2097152
        float4 v = *(const float4*)&src[(size_t)i4 * 4];
        ushort4 o;
        o.x = f2bf(v.x); o.y = f2bf(v.y); o.z = f2bf(v.z); o.w = f2bf(v.w);
        *(ushort4*)&dst[(size_t)i4 * 4] = o;
    }
}

// W[256][256] f32 -> Wt[n][k] bf16 (transposed)
__global__ __launch_bounds__(256) void cast_wt_kernel(
    const float* __restrict__ W, unsigned short* __restrict__ Wt) {
    __shared__ float tile[16][17];
    int tx = threadIdx.x & 15, ty = threadIdx.x >> 4;
    int bx = blockIdx.x, by = blockIdx.y;
    tile[ty][tx] = W[(size_t)(by * 16 + ty) * 256 + bx * 16 + tx];
    __syncthreads();
    // n = bx*16+ty, k = by*16+tx
    Wt[(size_t)(bx * 16 + ty) * 256 + by * 16 + tx] = f2bf(tile[tx][ty]);
}

// Y(bf16) = X(bf16, Mx256) @ W via Wt (bf16, transposed [n][k])
// block: 256 thr = 4 waves; tile 64 rows x 256 cols; MFMA 16x16x32
__global__ __launch_bounds__(256) void gemm_bf_kernel(
    const unsigned short* __restrict__ X, const unsigned short* __restrict__ Wt,
    unsigned short* __restrict__ Y) {
    __shared__ unsigned short Xs[64 * 40];    // row stride 40 (80B = 20 banks; 2-way max)
    __shared__ unsigned short Ws[256 * 40];
    const int t = threadIdx.x;
    const int L = t & 63, wv = t >> 6;
    const int q = L >> 4, n = L & 15;
    const size_t row0 = (size_t)blockIdx.x * 64;
    f32x4 acc[16];
#pragma unroll
    for (int nt = 0; nt < 16; ++nt) acc[nt] = (f32x4){0.f, 0.f, 0.f, 0.f};

    for (int k0 = 0; k0 < 256; k0 += 32) {
        {
            int r = t >> 2, seg = t & 3;
            *(uint4*)&Xs[r * 40 + seg * 8] =
                *(const uint4*)&X[(row0 + r) * 256 + k0 + seg * 8];
#pragma unroll
            for (int it = 0; it < 4; ++it) {
                int nn = (t >> 2) + it * 64;
                *(uint4*)&Ws[nn * 40 + seg * 8] =
                    *(const uint4*)&Wt[(size_t)nn * 256 + k0 + seg * 8];
            }
        }
        __syncthreads();
        bf16x8 av = *(const bf16x8*)&Xs[(wv * 16 + n) * 40 + q * 8];
#pragma unroll
        for (int nt = 0; nt < 16; ++nt) {
            bf16x8 bv = *(const bf16x8*)&Ws[(nt * 16 + n) * 40 + q * 8];
            acc[nt] = __builtin_amdgcn_mfma_f32_16x16x32_bf16(av, bv, acc[nt], 0, 0, 0);
        }
        __syncthreads();
    }
#pragma unroll
    for (int nt = 0; nt < 16; ++nt)
#pragma unroll
        for (int r = 0; r < 4; ++r) {
            size_t row = row0 + wv * 16 + q * 4 + r;
            Y[row * 256 + nt * 16 + n] = f2bf(acc[nt][r]);
        }
}

// y_bf16_out = LN(leaky_relu(y_bf16_in + bias)) * g + be ; optional row sq-norms
__global__ __launch_bounds__(256) void ln_bf_kernel(
    const unsigned short* __restrict__ Yin, unsigned short* __restrict__ Yout,
    const float* __restrict__ bias, const float* __restrict__ gam,
    const float* __restrict__ bet, float* __restrict__ norms) {
    int lane = threadIdx.x & 63;
    int wv = threadIdx.x >> 6;
    size_t row = (size_t)blockIdx.x * 4 + wv;
    ushort4 y4 = *(const ushort4*)&Yin[row * 256 + lane * 4];
    float4 b4 = *(const float4*)&bias[lane * 4];
    float h[4] = {bf2f(y4.x) + b4.x, bf2f(y4.y) + b4.y, bf2f(y4.z) + b4.z, bf2f(y4.w) + b4.w};
#pragma unroll
    for (int e = 0; e < 4; ++e) h[e] = h[e] >= 0.f ? h[e] : 0.01f * h[e];
    float s = h[0] + h[1] + h[2] + h[3];
    float sq = h[0] * h[0] + h[1] * h[1] + h[2] * h[2] + h[3] * h[3];
#pragma unroll
    for (int off = 32; off > 0; off >>= 1) {
        s += __shfl_down(s, off, 64);
        sq += __shfl_down(sq, off, 64);
    }
    s = __shfl(s, 0, 64); sq = __shfl(sq, 0, 64);
    float mean = s * (1.f / 256.f);
    float var = fmaxf(sq * (1.f / 256.f) - mean * mean, 0.f);
    float inv = rsqrtf(var + 1e-5f);
    float4 g4 = *(const float4*)&gam[lane * 4];
    float4 e4 = *(const float4*)&bet[lane * 4];
    float gv[4] = {g4.x, g4.y, g4.z, g4.w};
    float ev[4] = {e4.x, e4.y, e4.z, e4.w};
    ushort4 o4; float nr = 0.f;
    {
        unsigned short ob[4];
#pragma unroll
        for (int e = 0; e < 4; ++e) {
            float o = (h[e] - mean) * inv * gv[e] + ev[e];
            ob[e] = f2bf(o);
            float orr = bf2f(ob[e]);   // norm from the rounded value (consistent with MFMA dot)
            nr += orr * orr;
        }
        o4.x = ob[0]; o4.y = ob[1]; o4.z = ob[2]; o4.w = ob[3];
    }
    *(ushort4*)&Yout[row * 256 + lane * 4] = o4;
    if (norms) {
#pragma unroll
        for (int off = 32; off > 0; off >>= 1) nr += __shfl_down(nr, off, 64);
        if (lane == 0) norms[row] = nr;
    }
}

// cdist via MFMA + in/out loss partial + K(bf16) = exp(-2*cost)
// block 256 thr, tile 64x64, grid (8,8,64)
__global__ __launch_bounds__(256) void cost_mfma_kernel(
    const unsigned short* __restrict__ E, const float* __restrict__ norms,
    const int* __restrict__ argA, const int* __restrict__ argB,
    const float* __restrict__ pa, const float* __restrict__ pb,
    unsigned short* __restrict__ Kb16, float* __restrict__ acc) {
    __shared__ unsigned short As[64 * 40];
    __shared__ unsigned short Bs[64 * 40];
    const int t = threadIdx.x;
    const int L = t & 63, wv = t >> 6;
    const int q = L >> 4, n = L & 15;
    const int b = blockIdx.z;
    const int i0 = blockIdx.y * 64, j0 = blockIdx.x * 64;
    const unsigned short* eA = E + (size_t)b * 512 * 256;
    const unsigned short* eB = E + (size_t)(32768 + b * 512) * 256;
    f32x4 dot[4];
#pragma unroll
    for (int nt = 0; nt < 4; ++nt) dot[nt] = (f32x4){0.f, 0.f, 0.f, 0.f};

    for (int k0 = 0; k0 < 256; k0 += 32) {
        int r = t >> 2, seg = t & 3;
        *(uint4*)&As[r * 40 + seg * 8] =
            *(const uint4*)&eA[(size_t)(i0 + r) * 256 + k0 + seg * 8];
        *(uint4*)&Bs[r * 40 + seg * 8] =
            *(const uint4*)&eB[(size_t)(j0 + r) * 256 + k0 + seg * 8];
        __syncthreads();
        bf16x8 av = *(const bf16x8*)&As[(wv * 16 + n) * 40 + q * 8];
#pragma unroll
        for (int nt = 0; nt < 4; ++nt) {
            bf16x8 bv = *(const bf16x8*)&Bs[(nt * 16 + n) * 40 + q * 8];
            dot[nt] = __builtin_amdgcn_mfma_f32_16x16x32_bf16(av, bv, dot[nt], 0, 0, 0);
        }
        __syncthreads();
    }
    // epilogue: lane covers rows base+r (r=0..3), cols j0+nt*16+n
    int base_row = i0 + wv * 16 + q * 4;
    float nA[4], pA[4]; int cA[4];
#pragma unroll
    for (int r = 0; r < 4; ++r) {
        nA[r] = norms[b * 512 + base_row + r];
        pA[r] = pa[b * 512 + base_row + r];
        cA[r] = argA[b * 512 + base_row + r];
    }
    float part = 0.f;
#pragma unroll
    for (int nt = 0; nt < 4; ++nt) {
        int col = j0 + nt * 16 + n;
        float nB = norms[32768 + b * 512 + col];
        float pB = pb[b * 512 + col];
        int cB = argB[b * 512 + col];
#pragma unroll
        for (int r = 0; r < 4; ++r) {
            float d2 = nA[r] + nB - 2.f * dot[nt][r];
            float c = sqrtf(fmaxf(d2, 0.f));
            float pm = pA[r] * pB;
            float cc = c + (BIGF - BIGF * pm);
            float sgn = (cA[r] == cB) ? 1.f : -1.f;
            part += cc * sgn * pm;
            Kb16[((size_t)b * 512 + base_row + r) * 512 + col] = f2bf(expf(-2.f * cc));
        }
    }
    float tot = block_reduce_256(part);
    if (threadIdx.x == 0) atomicAdd(&acc[ACC_IN + b], tot);
}

// persistent Sinkhorn: one block per batch, 10 iterations, bf16 K
__global__ __launch_bounds__(1024) void sinkhorn_kernel(
    const unsigned short* __restrict__ Kb16, float* __restrict__ u, float* __restrict__ v) {
    int b = blockIdx.x;
    const unsigned short* Kb = Kb16 + (size_t)b * 262144;
    __shared__ float uv[512], vv[512];
    __shared__ float cp[4][512];
    int t = threadIdx.x;
    if (t < 512) uv[t] = 1.f / 512.f;
    __syncthreads();
    for (int it = 0; it < 10; ++it) {
        // v-step: col sums s_j = sum_i K[i][j] u_i
        {
            int c2 = t & 255, rq = t >> 8;                 // cols 2c2,2c2+1; rows rq*128..+128
            const unsigned short* base = Kb + (size_t)(rq * 128) * 512 + c2 * 2;
            float s0 = 0.f, s1 = 0.f;
#pragma unroll 8
            for (int i = 0; i < 128; ++i) {
                unsigned int w = *(const unsigned int*)(base + (size_t)i * 512);
                float k0 = __uint_as_float(w << 16);
                float k1 = __uint_as_float(w & 0xFFFF0000u);
                float ui = uv[rq * 128 + i];
                s0 = fmaf(k0, ui, s0);
                s1 = fmaf(k1, ui, s1);
            }
            cp[rq][c2 * 2] = s0; cp[rq][c2 * 2 + 1] = s1;
        }
        __syncthreads();
        if (t < 512) vv[t] = (1.f / 512.f) / (cp[0][t] + cp[1][t] + cp[2][t] + cp[3][t]);
        __syncthreads();
        // u-step: wave per 32 rows
        {
            int wv_ = t >> 6, l = t & 63;
            for (int rr = 0; rr < 32; ++rr) {
                int row = wv_ * 32 + rr;
                const unsigned short* rp = Kb + (size_t)row * 512 + l * 2;
                float s = 0.f;
#pragma unroll
                for (int c = 0; c < 4; ++c) {
                    unsigned int w = *(const unsigned int*)(rp + c * 128);
                    float k0 = __uint_as_float(w << 16);
                    float k1 = __uint_as_float(w & 0xFFFF0000u);
                    s = fmaf(k0, vv[c * 128 + l * 2], s);
                    s = fmaf(k1, vv[c * 128 + l * 2 + 1], s);
                }
#pragma unroll
                for (int off = 32; off > 0; off >>= 1) s += __shfl_down(s, off, 64);
                if (l == 0) uv[row] = (1.f / 512.f) / s;
            }
        }
        __syncthreads();
    }
    if (t < 512) {
        u[(size_t)b * 512 + t] = uv[t];
        v[(size_t)b * 512 + t] = vv[t];
    }
}

// sup loss on bf16 K
__global__ __launch_bounds__(256) void sup_kernel(
    const unsigned short* __restrict__ Kb16, const float* __restrict__ u,
    const float* __restrict__ v, const float* __restrict__ rel,
    const float* __restrict__ pa, float* __restrict__ acc) {
    const int nthreads = 4096 * 256;
    int tid = blockIdx.x * 256 + threadIdx.x;
    float part = 0.f;
#pragma unroll
    for (int k = 0; k < 4; ++k) {
        int i4 = tid + k * nthreads;            // group-of-4 index < 4,194,304
        int e = i4 * 4;
        int b = e >> 18;
        int i = (e >> 9) & 511;
        int j0 = e & 511;
        ushort4 K4 = *(const ushort4*)&Kb16[(size_t)i4 * 4];
        float4 r4 = *(const float4*)&rel[(size_t)i4 * 4];
        float4 v4 = *(const float4*)&v[b * 512 + j0];
        float ui = u[b * 512 + i] * 512.f;
        float pai = pa[b * 512 + i];
        float d0 = ui * bf2f(K4.x) * v4.x - r4.x;
        float d1 = ui * bf2f(K4.y) * v4.y - r4.y;
        float d2 = ui * bf2f(K4.z) * v4.z - r4.z;
        float d3 = ui * bf2f(K4.w) * v4.w - r4.w;
        part += (d0 * d0 + d1 * d1 + d2 * d2 + d3 * d3) * pai;
    }
    float tot = block_reduce_256(part);
    if (threadIdx.x == 0) atomicAdd(&acc[ACC_SUP + (blockIdx.x & 255)], tot);
}

__global__ __launch_bounds__(256) void final_kernel(const float* __restrict__ acc,
                                                    float* __restrict__ out) {
    int t = threadIdx.x;
    float vin = (t < 64) ? acc[ACC_IN + t] : 0.f;
    float sIn = block_reduce_256(vin);
    float vsup = acc[ACC_SUP + t];
    float sSup = block_reduce_256(vsup);
    if (t == 0)
        out[0] = sIn * (1.f / 16777216.f) + 10.f * sSup / acc[ACC_PA];
}

extern "C" void kernel_launch(void* const* d_in, const int* in_sizes, int n_in,
                              void* d_out, int out_size, void* d_ws, size_t ws_size,
                              hipStream_t stream) {
    const float* la  = (const float*)d_in[0];
    const float* lb  = (const float*)d_in[1];
    const float* xA  = (const float*)d_in[2];
    const float* xB  = (const float*)d_in[3];
    const float* rel = (const float*)d_in[4];
    const float* pa  = (const float*)d_in[5];
    const float* pb  = (const float*)d_in[6];
    const float* W1  = (const float*)d_in[7];
    const float* b1  = (const float*)d_in[8];
    const float* g1  = (const float*)d_in[9];
    const float* be1 = (const float*)d_in[10];
    const float* W2  = (const float*)d_in[11];
    const float* b2  = (const float*)d_in[12];
    const float* g2  = (const float*)d_in[13];
    const float* be2 = (const float*)d_in[14];
    float* out = (float*)d_out;

    float* ws = (float*)d_ws;
    unsigned short* Kb16 = (unsigned short*)(ws + KB_OFF);   // Ybf1/Ybf2 then K
    unsigned short* Xbf  = (unsigned short*)(ws + X_OFF);    // Xbf then Ebf
    unsigned short* Hbf  = (unsigned short*)(ws + H_OFF);
    float* norms = ws + NORM_OFF;
    float* u     = ws + U_OFF;
    float* v     = ws + V_OFF;
    int* argA    = (int*)(ws + ARGA_OFF);
    int* argB    = (int*)(ws + ARGB_OFF);
    float* acc   = ws + ACC_OFF;
    unsigned short* Wt1 = (unsigned short*)(ws + WT1_OFF);
    unsigned short* Wt2 = (unsigned short*)(ws + WT2_OFF);

    zero_acc_kernel<<<2, 256, 0, stream>>>(acc);
    argmax_pa_kernel<<<128, 256, 0, stream>>>(la, lb, pa, argA, argB, acc);

    // casts
    cast_bf_kernel<<<2048, 256, 0, stream>>>(xA, Xbf);
    cast_bf_kernel<<<2048, 256, 0, stream>>>(xB, Xbf + (size_t)MROWS * DIM);
    cast_wt_kernel<<<dim3(16, 16), 256, 0, stream>>>(W1, Wt1);
    cast_wt_kernel<<<dim3(16, 16), 256, 0, stream>>>(W2, Wt2);

    // layer 1
    gemm_bf_kernel<<<1024, 256, 0, stream>>>(Xbf, Wt1, Kb16);
    ln_bf_kernel<<<16384, 256, 0, stream>>>(Kb16, Hbf, b1, g1, be1, nullptr);
    // layer 2
    gemm_bf_kernel<<<1024, 256, 0, stream>>>(Hbf, Wt2, Kb16);
    ln_bf_kernel<<<16384, 256, 0, stream>>>(Kb16, Xbf, b2, g2, be2, norms);  // Ebf -> Xbf buf

    // cost + K (bf16, overwrites Ybf2)
    cost_mfma_kernel<<<dim3(8, 8, 64), 256, 0, stream>>>(Xbf, norms, argA, argB, pa, pb, Kb16, acc);

    // sinkhorn: single persistent launch
    sinkhorn_kernel<<<64, 1024, 0, stream>>>(Kb16, u, v);

    sup_kernel<<<4096, 256, 0, stream>>>(Kb16, u, v, rel, pa, acc);
    final_kernel<<<1, 256, 0, stream>>>(acc, out);
}